// Round 2
// baseline (640.494 us; speedup 1.0000x reference)
//
#include <hip/hip_runtime.h>

// MeanAggregator: out[b, :] = mean_k features[neigh_idx[b,k], :]
// U=1e6, D=128, B=1e5, K=10.  Pure memory-bound gather-reduce.
//
// 32 threads per output row, each thread owns one float4 column chunk
// (32 x 16 B = 512 B = one full feature row per gather -> coalesced).
// All 10 gathers are written as explicitly independent loads so the
// compiler issues them back-to-back (one vmcnt drain, max MLP).

#define AGG_D 128
#define AGG_K 10

__global__ __launch_bounds__(256) void MeanAggregator_43946105372917_kernel(
    const float* __restrict__ features,
    const int*   __restrict__ neigh_idx,
    float*       __restrict__ out,
    int B)
{
    const int tid = blockIdx.x * blockDim.x + threadIdx.x;
    const int row = tid >> 5;            // 32 threads per output row
    const int col = (tid & 31) << 2;     // float4 column offset
    if (row >= B) return;

    // 40 B of indices as 5 x int2 (row*40 is 8B-aligned).
    const int2* __restrict__ ip = (const int2*)(neigh_idx + row * AGG_K);
    const int2 i01 = ip[0];
    const int2 i23 = ip[1];
    const int2 i45 = ip[2];
    const int2 i67 = ip[3];
    const int2 i89 = ip[4];

    const float* __restrict__ base = features + col;

    // 10 independent gathers, no accumulation chain between loads.
    const float4 v0 = *(const float4*)(base + (size_t)i01.x * AGG_D);
    const float4 v1 = *(const float4*)(base + (size_t)i01.y * AGG_D);
    const float4 v2 = *(const float4*)(base + (size_t)i23.x * AGG_D);
    const float4 v3 = *(const float4*)(base + (size_t)i23.y * AGG_D);
    const float4 v4 = *(const float4*)(base + (size_t)i45.x * AGG_D);
    const float4 v5 = *(const float4*)(base + (size_t)i45.y * AGG_D);
    const float4 v6 = *(const float4*)(base + (size_t)i67.x * AGG_D);
    const float4 v7 = *(const float4*)(base + (size_t)i67.y * AGG_D);
    const float4 v8 = *(const float4*)(base + (size_t)i89.x * AGG_D);
    const float4 v9 = *(const float4*)(base + (size_t)i89.y * AGG_D);

    // Pairwise sum tree.
    float4 s01, s23, s45, s67, s89, t0, t1, t2, r;
    s01.x = v0.x + v1.x; s01.y = v0.y + v1.y; s01.z = v0.z + v1.z; s01.w = v0.w + v1.w;
    s23.x = v2.x + v3.x; s23.y = v2.y + v3.y; s23.z = v2.z + v3.z; s23.w = v2.w + v3.w;
    s45.x = v4.x + v5.x; s45.y = v4.y + v5.y; s45.z = v4.z + v5.z; s45.w = v4.w + v5.w;
    s67.x = v6.x + v7.x; s67.y = v6.y + v7.y; s67.z = v6.z + v7.z; s67.w = v6.w + v7.w;
    s89.x = v8.x + v9.x; s89.y = v8.y + v9.y; s89.z = v8.z + v9.z; s89.w = v8.w + v9.w;
    t0.x = s01.x + s23.x; t0.y = s01.y + s23.y; t0.z = s01.z + s23.z; t0.w = s01.w + s23.w;
    t1.x = s45.x + s67.x; t1.y = s45.y + s67.y; t1.z = s45.z + s67.z; t1.w = s45.w + s67.w;
    t2.x = t0.x + t1.x;   t2.y = t0.y + t1.y;   t2.z = t0.z + t1.z;   t2.w = t0.w + t1.w;

    const float sc = 1.0f / (float)AGG_K;
    r.x = (t2.x + s89.x) * sc;
    r.y = (t2.y + s89.y) * sc;
    r.z = (t2.z + s89.z) * sc;
    r.w = (t2.w + s89.w) * sc;

    *(float4*)(out + (size_t)row * AGG_D + col) = r;
}

extern "C" void kernel_launch(void* const* d_in, const int* in_sizes, int n_in,
                              void* d_out, int out_size, void* d_ws, size_t ws_size,
                              hipStream_t stream) {
    const float* features  = (const float*)d_in[0];
    const int*   neigh_idx = (const int*)d_in[1];
    float*       out       = (float*)d_out;

    const int B = in_sizes[1] / AGG_K;          // 100000
    const int total_threads = B * 32;           // 32 lanes per row
    const int block = 256;
    const int grid  = (total_threads + block - 1) / block;

    MeanAggregator_43946105372917_kernel<<<grid, block, 0, stream>>>(
        features, neigh_idx, out, B);
}